// Round 1
// baseline (41383.035 us; speedup 1.0000x reference)
//
#include <hip/hip_runtime.h>
#include <math.h>

#define BB 32
#define TT 500
#define FF 640
#define HH 640
#define JJ 640
#define VV 1024
#define G4 2560

// ws layout (float offsets)
//  ENC   : 0          (16000*640 = 10,240,000)
//  EW    : 10,240,000 (1024*2560 =  2,621,440)
//  h     : 12,861,440 (32*640)
//  c     : 12,881,920 (32*640)
//  Tt    : 12,902,400 (32*640)
//  G     : 12,922,880 (32*2560)
//  amax  : 13,004,800 (32 x u64 = 64 floats, 8B aligned)
//  sumexp: 13,004,864 (32)
//  scores: 13,004,896 (32)
// total ~13,004,928 floats = 52.0 MB

__device__ __forceinline__ float sigf(float x) { return 1.0f / (1.0f + expf(-x)); }

__device__ __forceinline__ unsigned int fkey(float x) {
    unsigned int u = __float_as_uint(x);
    return (u & 0x80000000u) ? ~u : (u | 0x80000000u);
}

__device__ __forceinline__ unsigned long long shflxor_u64(unsigned long long v, int m) {
    unsigned int lo = (unsigned int)v, hi = (unsigned int)(v >> 32);
    lo = (unsigned int)__shfl_xor((int)lo, m);
    hi = (unsigned int)__shfl_xor((int)hi, m);
    return ((unsigned long long)hi << 32) | lo;
}

// C[M,N] = A[M,K] @ B[K,N] + bias[N]   (all row-major f32)
__global__ __launch_bounds__(256) void gemm_bias_kernel(
    const float* __restrict__ A, const float* __restrict__ Bm,
    const float* __restrict__ bias, float* __restrict__ C,
    int M, int N, int K)
{
    __shared__ float As[16][65];
    __shared__ float Bs[16][64];
    int tid = threadIdx.x;
    int m0 = blockIdx.y * 64, n0 = blockIdx.x * 64;
    int ar = tid >> 2, ac = (tid & 3) * 4;
    int br4 = (tid >> 6) * 4, bc = tid & 63;
    int ty = tid >> 4, tx = tid & 15;
    float acc[4][4] = {};
    for (int k0 = 0; k0 < K; k0 += 16) {
        float4 av = *(const float4*)(A + (long)(m0 + ar) * K + k0 + ac);
        As[ac + 0][ar] = av.x; As[ac + 1][ar] = av.y;
        As[ac + 2][ar] = av.z; As[ac + 3][ar] = av.w;
#pragma unroll
        for (int i = 0; i < 4; ++i)
            Bs[br4 + i][bc] = Bm[(long)(k0 + br4 + i) * N + n0 + bc];
        __syncthreads();
#pragma unroll
        for (int kk = 0; kk < 16; ++kk) {
            float a[4], b[4];
#pragma unroll
            for (int i = 0; i < 4; ++i) a[i] = As[kk][ty * 4 + i];
#pragma unroll
            for (int j = 0; j < 4; ++j) b[j] = Bs[kk][tx * 4 + j];
#pragma unroll
            for (int i = 0; i < 4; ++i)
#pragma unroll
                for (int j = 0; j < 4; ++j)
                    acc[i][j] = fmaf(a[i], b[j], acc[i][j]);
        }
        __syncthreads();
    }
#pragma unroll
    for (int i = 0; i < 4; ++i)
#pragma unroll
        for (int j = 0; j < 4; ++j)
            C[(long)(m0 + ty * 4 + i) * N + n0 + tx * 4 + j] =
                acc[i][j] + bias[n0 + tx * 4 + j];
}

// h1,c1 from token BLANK with zero state; broadcast to all batches; zero step buffers.
__global__ void init_kernel(const float* __restrict__ EW, float* __restrict__ h,
                            float* __restrict__ c, float* __restrict__ scores,
                            unsigned long long* __restrict__ amax,
                            float* __restrict__ sumexp)
{
    int tid = threadIdx.x;
    for (int j = tid; j < HH; j += 256) {
        float gi = EW[j], gg = EW[1280 + j], go = EW[1920 + j];
        float c1 = sigf(gi) * tanhf(gg);   // sig(f)*c0 term is 0
        float h1 = sigf(go) * tanhf(c1);
        for (int b = 0; b < BB; ++b) { h[b * 640 + j] = h1; c[b * 640 + j] = c1; }
    }
    if (tid < 32) { scores[tid] = 0.f; sumexp[tid] = 0.f; amax[tid] = 0ull; }
}

// Phase A: u = h @ [W_dec | W_hh];  Tt = tanh(ENC + u_dec),  G = u_hh
// grid 200 WGs x 256 thr; WG covers 16 concat-cols; thread = (batch, col-pair)
__global__ __launch_bounds__(256) void step_a_kernel(
    const float* __restrict__ h, const float* __restrict__ Wdec,
    const float* __restrict__ Whh, const float* __restrict__ ENC,
    float* __restrict__ Tt, float* __restrict__ G, int t)
{
    int tid = threadIdx.x;
    int b = tid >> 3;
    int c = blockIdx.x * 16 + (tid & 7) * 2;
    const float* Wp; int stride, cc;
    if (c < 640) { Wp = Wdec; stride = 640;  cc = c; }
    else         { Wp = Whh;  stride = 2560; cc = c - 640; }
    const float* hb = h + b * 640;
    const float* w = Wp + cc;
    float ax = 0.f, ay = 0.f;
    for (int k0 = 0; k0 < 640; k0 += 4) {
        float4 hv = *(const float4*)(hb + k0);
        float2 w0 = *(const float2*)(w);
        float2 w1 = *(const float2*)(w + stride);
        float2 w2 = *(const float2*)(w + 2 * stride);
        float2 w3 = *(const float2*)(w + 3 * stride);
        w += 4 * stride;
        ax = fmaf(hv.x, w0.x, ax); ay = fmaf(hv.x, w0.y, ay);
        ax = fmaf(hv.y, w1.x, ax); ay = fmaf(hv.y, w1.y, ay);
        ax = fmaf(hv.z, w2.x, ax); ay = fmaf(hv.z, w2.y, ay);
        ax = fmaf(hv.w, w3.x, ax); ay = fmaf(hv.w, w3.y, ay);
    }
    if (c < 640) {
        const float* e = ENC + ((long)b * TT + t) * 640;
        Tt[b * 640 + c]     = tanhf(e[c] + ax);
        Tt[b * 640 + c + 1] = tanhf(e[c + 1] + ay);
    } else {
        G[b * 2560 + cc] = ax;
        G[b * 2560 + cc + 1] = ay;
    }
}

// Phase B: logits = Tt @ W_out + b_out; cross-WG argmax via u64 atomicMax
// (order-preserving float key, first-index tie-break) + sumexp via atomicAdd.
// grid 128 WGs x 256 thr; thread = (batch, one col)
__global__ __launch_bounds__(256) void step_b_kernel(
    const float* __restrict__ Tt, const float* __restrict__ Wout,
    const float* __restrict__ bout, unsigned long long* __restrict__ amax,
    float* __restrict__ sumexp)
{
    int tid = threadIdx.x;
    int b = tid >> 3;
    int c = blockIdx.x * 8 + (tid & 7);
    const float* tb = Tt + b * 640;
    const float* w = Wout + c;
    float acc = 0.f;
    for (int k0 = 0; k0 < 640; k0 += 4) {
        float4 tv = *(const float4*)(tb + k0);
        acc = fmaf(tv.x, w[0], acc);
        acc = fmaf(tv.y, w[1024], acc);
        acc = fmaf(tv.z, w[2048], acc);
        acc = fmaf(tv.w, w[3072], acc);
        w += 4096;
    }
    float logit = acc + bout[c];
    unsigned long long packed =
        ((unsigned long long)fkey(logit) << 32) | (unsigned int)(1023 - c);
    float sexp = expf(logit);
#pragma unroll
    for (int m = 4; m >= 1; m >>= 1) {
        unsigned long long o = shflxor_u64(packed, m);
        if (o > packed) packed = o;
        sexp += __shfl_xor(sexp, m);
    }
    if ((tid & 7) == 0) {
        atomicMax(amax + b, packed);
        atomicAdd(sumexp + b, sexp);
    }
}

// Phase C: read argmax, emit token, update scores + LSTM state; reset step buffers.
// grid 32 WGs (one per batch) x 256 thr
__global__ __launch_bounds__(256) void step_c_kernel(
    unsigned long long* __restrict__ amax, float* __restrict__ sumexp,
    const float* __restrict__ EW, const float* __restrict__ G,
    float* __restrict__ h, float* __restrict__ c, float* __restrict__ scores,
    float* __restrict__ out, int t)
{
    __shared__ int s_tok, s_emit;
    int b = blockIdx.x, tid = threadIdx.x;
    if (tid == 0) {
        unsigned long long p = amax[b];
        int tok = 1023 - (int)(p & 0xFFFFFFFFu);
        unsigned int key = (unsigned int)(p >> 32);
        unsigned int u = (key & 0x80000000u) ? (key ^ 0x80000000u) : ~key;
        float maxlogit = __uint_as_float(u);
        int emit = (tok != 0);
        out[b * TT + t] = (float)tok;   // out_tok == tok always (BLANK==0)
        if (emit) scores[b] += maxlogit - logf(sumexp[b]);
        amax[b] = 0ull; sumexp[b] = 0.f;
        s_tok = tok; s_emit = emit;
    }
    __syncthreads();
    if (!s_emit) return;
    int tok = s_tok;
    const float* ew = EW + (long)tok * 2560;
    const float* gb = G + b * 2560;
    for (int j = tid; j < 640; j += 256) {
        float gi = ew[j] + gb[j];
        float gf = ew[640 + j] + gb[640 + j];
        float gg = ew[1280 + j] + gb[1280 + j];
        float go = ew[1920 + j] + gb[1920 + j];
        float cn = sigf(gf) * c[b * 640 + j] + sigf(gi) * tanhf(gg);
        float hn = sigf(go) * tanhf(cn);
        c[b * 640 + j] = cn;
        h[b * 640 + j] = hn;
    }
}

__global__ void final_kernel(const float* __restrict__ scores, float* __restrict__ out)
{
    if (threadIdx.x == 0) {
        float s = 0.f;
        for (int b = 0; b < 32; ++b) s += expf(scores[b]);
        out[16000] = s / 32.0f;
    }
}

extern "C" void kernel_launch(void* const* d_in, const int* in_sizes, int n_in,
                              void* d_out, int out_size, void* d_ws, size_t ws_size,
                              hipStream_t stream)
{
    const float* X     = (const float*)d_in[0];  // tn_output (32,500,640)
    const float* E     = (const float*)d_in[1];  // (1024,640)
    const float* W_ih  = (const float*)d_in[2];  // (640,2560)
    const float* W_hh  = (const float*)d_in[3];  // (640,2560)
    const float* b_l   = (const float*)d_in[4];  // (2560)
    const float* W_enc = (const float*)d_in[5];  // (640,640)
    const float* W_dec = (const float*)d_in[6];  // (640,640)
    const float* b_j   = (const float*)d_in[7];  // (640)
    const float* W_out = (const float*)d_in[8];  // (640,1024)
    const float* b_out = (const float*)d_in[9];  // (1024)

    float* ws  = (float*)d_ws;
    float* ENC = ws;
    float* EW  = ws + 10240000;
    float* h   = ws + 12861440;
    float* c   = ws + 12881920;
    float* Tt  = ws + 12902400;
    float* G   = ws + 12922880;
    unsigned long long* amax = (unsigned long long*)(ws + 13004800);
    float* sumexp = ws + 13004864;
    float* scores = ws + 13004896;
    float* out = (float*)d_out;

    // Precompute: ENC = X @ W_enc + b_j   (16000x640, K=640)
    gemm_bias_kernel<<<dim3(10, 250), 256, 0, stream>>>(X, W_enc, b_j, ENC, 16000, 640, 640);
    // Precompute: EW = E @ W_ih + b_lstm  (1024x2560, K=640)
    gemm_bias_kernel<<<dim3(40, 16), 256, 0, stream>>>(E, W_ih, b_l, EW, 1024, 2560, 640);
    init_kernel<<<1, 256, 0, stream>>>(EW, h, c, scores, amax, sumexp);

    for (int t = 0; t < TT; ++t) {
        step_a_kernel<<<200, 256, 0, stream>>>(h, W_dec, W_hh, ENC, Tt, G, t);
        step_b_kernel<<<128, 256, 0, stream>>>(Tt, W_out, b_out, amax, sumexp);
        step_c_kernel<<<32, 256, 0, stream>>>(amax, sumexp, EW, G, h, c, scores, out, t);
    }
    final_kernel<<<1, 64, 0, stream>>>(scores, out);
}